// Round 7
// baseline (258.829 us; speedup 1.0000x reference)
//
#include <hip/hip_runtime.h>

typedef __attribute__((ext_vector_type(4))) float f32x4;
typedef __attribute__((ext_vector_type(8))) short s16x8;

#define NTOK 65536
#define KEXT 1088  // [512 ia3*Wb | 512 We | 8 4*ia3*B | ia3*bb | be | 54 zero]

__device__ __forceinline__ unsigned short f2b(float f) {
    unsigned int u = __float_as_uint(f);
    u = (u + 0x7FFFu + ((u >> 16) & 1u)) >> 16;
    return (unsigned short)u;
}

__device__ __forceinline__ void gld_lds16(const void* g, void* l) {
    __builtin_amdgcn_global_load_lds(
        (const __attribute__((address_space(1))) unsigned int*)g,
        (__attribute__((address_space(3))) unsigned int*)l, 16, 0, 0);
}

// ---------------- P1: build Wcat[e][512 cols][KEXT] bf16 (plain layout) -----
__global__ __launch_bounds__(256) void prep_kernel(
    const float* __restrict__ Wb, const float* __restrict__ bb,
    const float* __restrict__ B, const float* __restrict__ ia3,
    const float* __restrict__ We, const float* __restrict__ be,
    unsigned short* __restrict__ Wcat, int* __restrict__ cnt)
{
    int i = blockIdx.x * 256 + threadIdx.x;
    if (i < 4) cnt[i] = 0;
    if (i >= 4 * 512 * KEXT) return;
    const int k = i % KEXT;
    const int r = (i / KEXT) & 511;
    const int e = i / (KEXT * 512);
    float v;
    if (k < 512)        v = Wb[r * 512 + k] * ia3[r];
    else if (k < 1024)  v = We[((size_t)e * 512 + r) * 512 + (k - 512)];
    else if (k < 1032)  v = B[(k - 1024) * 512 + r] * 4.0f * ia3[r];
    else if (k == 1032) v = bb[r] * ia3[r];
    else if (k == 1033) v = be[e * 512 + r];
    else                v = 0.0f;
    Wcat[i] = f2b(v);
}

// ---------------- P2: router + LoRA-t + expert compaction -------------------
__global__ __launch_bounds__(256) void router_kernel(
    const float* __restrict__ x, const float* __restrict__ A,
    const float* __restrict__ Wr, const float* __restrict__ br,
    float* __restrict__ wgt, float* __restrict__ tws,
    int* __restrict__ perm, int* __restrict__ cnt)
{
    __shared__ int sCnt[4];
    __shared__ int sBase[4];
    __shared__ int sE[64];
    __shared__ int sPos[64];

    const int tid = threadIdx.x;
    const int wave = tid >> 6, lane = tid & 63;
    const int k0 = lane * 8;

    f32x4 wrv[4][2];
#pragma unroll
    for (int e = 0; e < 4; ++e) {
        wrv[e][0] = *(const f32x4*)(Wr + e * 512 + k0);
        wrv[e][1] = *(const f32x4*)(Wr + e * 512 + k0 + 4);
    }
    f32x4 av[8][2];
#pragma unroll
    for (int j = 0; j < 8; ++j) {
        av[j][0] = *(const f32x4*)(A + (size_t)(k0 + j) * 8);
        av[j][1] = *(const f32x4*)(A + (size_t)(k0 + j) * 8 + 4);
    }
    const float br0 = br[0], br1 = br[1], br2 = br[2], br3 = br[3];

    if (tid < 4) sCnt[tid] = 0;
    __syncthreads();

    const int tok0 = blockIdx.x * 64 + wave * 16;
    for (int it = 0; it < 16; ++it) {
        const int tok = tok0 + it;
        const float* xr = x + (size_t)tok * 512 + k0;
        f32x4 x0 = *(const f32x4*)xr;
        f32x4 x1 = *(const f32x4*)(xr + 4);
        float ar[4] = {0.f, 0.f, 0.f, 0.f};
        float at[8] = {0.f, 0.f, 0.f, 0.f, 0.f, 0.f, 0.f, 0.f};
#pragma unroll
        for (int j = 0; j < 8; ++j) {
            const float xv = (j < 4) ? x0[j] : x1[j - 4];
#pragma unroll
            for (int e = 0; e < 4; ++e) ar[e] += xv * wrv[e][j >> 2][j & 3];
#pragma unroll
            for (int r = 0; r < 8; ++r) at[r] += xv * av[j][r >> 2][r & 3];
        }
#pragma unroll
        for (int off = 32; off >= 1; off >>= 1) {
#pragma unroll
            for (int e = 0; e < 4; ++e) ar[e] += __shfl_xor(ar[e], off);
#pragma unroll
            for (int r = 0; r < 8; ++r) at[r] += __shfl_xor(at[r], off);
        }
        if (lane == 0) {
            const float l0 = ar[0] + br0, l1 = ar[1] + br1;
            const float l2 = ar[2] + br2, l3 = ar[3] + br3;
            int e = 0; float m = l0;
            if (l1 > m) { m = l1; e = 1; }
            if (l2 > m) { m = l2; e = 2; }
            if (l3 > m) { m = l3; e = 3; }
            const float s = expf(l0 - m) + expf(l1 - m) + expf(l2 - m) + expf(l3 - m);
            wgt[tok] = 1.0f / s;  // top value is exp(0)=1
            float* tp = tws + (size_t)tok * 8;
#pragma unroll
            for (int r = 0; r < 8; ++r) tp[r] = at[r];
            const int slot = wave * 16 + it;
            sE[slot] = e;
            sPos[slot] = atomicAdd(&sCnt[e], 1);
        }
    }
    __syncthreads();
    if (tid < 4) sBase[tid] = atomicAdd(&cnt[tid], sCnt[tid]);
    __syncthreads();
    if (tid < 64) {
        const int e = sE[tid];
        perm[e * NTOK + sBase[e] + sPos[tid]] = blockIdx.x * 64 + tid;
    }
}

// ---------------- P3: m97-clone 128x128 tile, 4 indep blocks/CU -------------
// 256 thr / 4 waves, wave-tile 64x64 (acc 64), single-buffered 32 KB LDS,
// launch_bounds(256,4) caps regs at 128 -> 4 co-resident blocks per CU whose
// barrier drains interleave (m114 overlap). bid&7 -> XCD: e = xcd>>1, m-tile
// parity = xcd&1; all 4 n-tiles of a token tile land on the same XCD.
__global__ __launch_bounds__(256, 4) void main_kernel(
    const float* __restrict__ x, const unsigned short* __restrict__ Wcat,
    const float* __restrict__ wgt, const float* __restrict__ tws,
    const int* __restrict__ perm, const int* __restrict__ cnt,
    float* __restrict__ out)
{
    __shared__ unsigned short sA[128 * 64];   // 16 KB
    __shared__ unsigned short sB[128 * 64];   // 16 KB

    const int bid = blockIdx.x;
    const int xcd = bid & 7;
    const int e = xcd >> 1;
    const int par = xcd & 1;
    const int r = bid >> 3;                  // 0..1023
    const int mt = ((r >> 2) << 1) | par;    // 0..511
    const int nt = r & 3;                    // n-tile (128 cols)
    const int n = cnt[e];
    const int base = mt * 128;
    if (base >= n) return;
    const int mcount = min(128, n - base);

    const int tid = threadIdx.x;
    const int lane = tid & 63;
    const int wave = tid >> 6;      // 0..3
    const int lanelo = lane & 15;
    const int g = lane >> 4;        // 0..3
    const int mw = wave >> 1;       // 0..1
    const int nw2 = wave & 1;       // 0..1

    // ---- A staging map: thread -> (row 0..127, k-quarter 0..1 of 32 elems) --
    const int arow = tid & 127;
    const int kq = tid >> 7;
    const int atok = perm[e * NTOK + base + min(arow, mcount - 1)];
    const float* axp = x + (size_t)atok * 512 + kq * 32;
    const float aw = wgt[atok];
    char* const aBase = (char*)sA + arow * 128;
    const int ars = arow & 7;

    // ---- B staging: 4 gld groups/wave, pre-swizzled source, linear dest ----
    const unsigned short* wcE = Wcat + ((size_t)e * 512 + nt * 128) * KEXT;
    const unsigned short* bsrc[4];
    int bdst[4];
#pragma unroll
    for (int i = 0; i < 4; ++i) {
        const int gi = i * 4 + wave;              // 0..15 row-groups of 8
        const int wr = gi * 8 + (lane >> 3);      // 0..127 (out col in n-tile)
        const int G = (lane & 7) ^ (wr & 7);      // swizzled source granule
        bsrc[i] = wcE + (size_t)wr * KEXT + G * 8;
        bdst[i] = gi * 1024;
    }

    f32x4 acc[4][4];
#pragma unroll
    for (int mb = 0; mb < 4; ++mb)
#pragma unroll
        for (int nb = 0; nb < 4; ++nb) acc[mb][nb] = (f32x4){0.f, 0.f, 0.f, 0.f};

    for (int c = 0; c < 17; ++c) {
        // early-issue first A batch (register-only; safe across the barrier)
        f32x4 q0, q1, q2, q3;
        if (c < 16) {
            const float* s = axp + ((c & 7) << 6);
            q0 = *(const f32x4*)s;        q1 = *(const f32x4*)(s + 4);
            q2 = *(const f32x4*)(s + 8);  q3 = *(const f32x4*)(s + 12);
        }
        __syncthreads();                 // all waves done reading sA/sB
        // B: 4 fire-and-forget gld_lds into LDS
#pragma unroll
        for (int i = 0; i < 4; ++i)
            gld_lds16(bsrc[i] + c * 64, (char*)sB + bdst[i]);
        // A: cvt + swizzled ds_write (2 batches of 16 f32)
        if (c < 16) {
            const float sc = (c >= 8) ? aw : 1.0f;
            s16x8 hv;
#pragma unroll
            for (int j = 0; j < 4; ++j) { hv[j] = (short)f2b(sc * q0[j]); hv[j + 4] = (short)f2b(sc * q1[j]); }
            *(s16x8*)(aBase + (((kq * 4 + 0) ^ ars) << 4)) = hv;
#pragma unroll
            for (int j = 0; j < 4; ++j) { hv[j] = (short)f2b(sc * q2[j]); hv[j + 4] = (short)f2b(sc * q3[j]); }
            *(s16x8*)(aBase + (((kq * 4 + 1) ^ ars) << 4)) = hv;
            const float* s2 = axp + ((c & 7) << 6) + 16;
            q0 = *(const f32x4*)s2;        q1 = *(const f32x4*)(s2 + 4);
            q2 = *(const f32x4*)(s2 + 8);  q3 = *(const f32x4*)(s2 + 12);
#pragma unroll
            for (int j = 0; j < 4; ++j) { hv[j] = (short)f2b(sc * q0[j]); hv[j + 4] = (short)f2b(sc * q1[j]); }
            *(s16x8*)(aBase + (((kq * 4 + 2) ^ ars) << 4)) = hv;
#pragma unroll
            for (int j = 0; j < 4; ++j) { hv[j] = (short)f2b(sc * q2[j]); hv[j + 4] = (short)f2b(sc * q3[j]); }
            *(s16x8*)(aBase + (((kq * 4 + 3) ^ ars) << 4)) = hv;
        } else {
            // tail chunk: cols 1024.. = [t0..t7 | 1, w, 0.. | zeros]
            s16x8 hv;
#pragma unroll
            for (int j = 0; j < 8; ++j) hv[j] = 0;
            if (kq == 0) {
                const float* atp = tws + (size_t)atok * 8;
                const f32x4 t0 = *(const f32x4*)atp;
                const f32x4 t1 = *(const f32x4*)(atp + 4);
                s16x8 ht;
#pragma unroll
                for (int j = 0; j < 4; ++j) { ht[j] = (short)f2b(t0[j]); ht[j + 4] = (short)f2b(t1[j]); }
                *(s16x8*)(aBase + ((0 ^ ars) << 4)) = ht;
                s16x8 h1 = hv;
                h1[0] = (short)f2b(1.0f);
                h1[1] = (short)f2b(aw);
                *(s16x8*)(aBase + ((1 ^ ars) << 4)) = h1;
                *(s16x8*)(aBase + ((2 ^ ars) << 4)) = hv;
                *(s16x8*)(aBase + ((3 ^ ars) << 4)) = hv;
            } else {
#pragma unroll
                for (int G = 4; G < 8; ++G)
                    *(s16x8*)(aBase + ((G ^ ars) << 4)) = hv;
            }
        }
        __syncthreads();                 // drains vmcnt(0)+lgkm: chunk c ready
        // ---- compute chunk c ----
#pragma unroll
        for (int kk = 0; kk < 2; ++kk) {
            s16x8 a[4];
#pragma unroll
            for (int mb = 0; mb < 4; ++mb) {
                const int row = mw * 64 + mb * 16 + lanelo;
                a[mb] = *(const s16x8*)((const char*)sA + row * 128 + ((((kk << 2) + g) ^ (row & 7)) << 4));
            }
#pragma unroll
            for (int nb = 0; nb < 4; ++nb) {
                const int wr = nw2 * 64 + nb * 16 + lanelo;
                const s16x8 b = *(const s16x8*)((const char*)sB + wr * 128 + ((((kk << 2) + g) ^ (wr & 7)) << 4));
#pragma unroll
                for (int mb = 0; mb < 4; ++mb)
                    acc[mb][nb] = __builtin_amdgcn_mfma_f32_16x16x32_bf16(a[mb], b, acc[mb][nb], 0, 0, 0);
            }
        }
    }

    // ---- epilogue: bare scattered store ----
    const int col0 = nt * 128 + nw2 * 64 + lanelo;
#pragma unroll
    for (int mb = 0; mb < 4; ++mb) {
#pragma unroll
        for (int rr = 0; rr < 4; ++rr) {
            const int trow = mw * 64 + mb * 16 + g * 4 + rr;
            if (trow < mcount) {
                const int tok = perm[e * NTOK + base + trow];
                float* orow = out + (size_t)tok * 512 + col0;
                orow[0]  = acc[mb][0][rr];
                orow[16] = acc[mb][1][rr];
                orow[32] = acc[mb][2][rr];
                orow[48] = acc[mb][3][rr];
            }
        }
    }
}

extern "C" void kernel_launch(void* const* d_in, const int* in_sizes, int n_in,
                              void* d_out, int out_size, void* d_ws, size_t ws_size,
                              hipStream_t stream)
{
    const float* x   = (const float*)d_in[0];
    const float* Wb  = (const float*)d_in[1];
    const float* bb  = (const float*)d_in[2];
    const float* A   = (const float*)d_in[3];
    const float* B   = (const float*)d_in[4];
    const float* ia3 = (const float*)d_in[5];
    const float* Wr  = (const float*)d_in[6];
    const float* br  = (const float*)d_in[7];
    const float* We  = (const float*)d_in[8];
    const float* be  = (const float*)d_in[9];
    float* out = (float*)d_out;

    char* w = (char*)d_ws;
    int* cnt             = (int*)w;                      // 256 B
    unsigned short* Wcat = (unsigned short*)(w + 256);   // 4*512*1088*2 = 4456448
    float* wgt           = (float*)(w + 4456704);        // 65536*4
    float* tws           = (float*)(w + 4718848);        // 65536*8*4
    int* perm            = (int*)(w + 6816000);          // 4*65536*4 -> end 7864576

    hipLaunchKernelGGL(prep_kernel, dim3(8704), dim3(256), 0, stream,
                       Wb, bb, B, ia3, We, be, Wcat, cnt);
    hipLaunchKernelGGL(router_kernel, dim3(1024), dim3(256), 0, stream,
                       x, A, Wr, br, wgt, tws, perm, cnt);
    hipLaunchKernelGGL(main_kernel, dim3(8192), dim3(256), 0, stream,
                       x, Wcat, wgt, tws, perm, cnt, out);
}